// Round 6
// baseline (206.289 us; speedup 1.0000x reference)
//
#include <hip/hip_runtime.h>
#include <hip/hip_bf16.h>
#include <stdint.h>

#define D_DIM 1024
#define R_DIM 128
#define NIN   8
#define M_TOT 16384

typedef unsigned short u16;
typedef __attribute__((ext_vector_type(4))) float f32x4;
typedef __attribute__((ext_vector_type(8))) __bf16 bf16x8;

__device__ __forceinline__ u16 f2b(float f) {
    union { float f; uint32_t u; } v; v.f = f;
    uint32_t r = (v.u + 0x7FFFu + ((v.u >> 16) & 1u)) >> 16;
    return (u16)r;
}

__device__ __forceinline__ void gload16(const void* g, void* l) {
    __builtin_amdgcn_global_load_lds(
        (const __attribute__((address_space(1))) uint32_t*)g,
        (__attribute__((address_space(3))) uint32_t*)l, 16, 0, 0);
}

#define SBAR  do { asm volatile("" ::: "memory"); __builtin_amdgcn_s_barrier(); asm volatile("" ::: "memory"); } while (0)
#define SBARL do { asm volatile("s_waitcnt lgkmcnt(0)" ::: "memory"); __builtin_amdgcn_s_barrier(); asm volatile("" ::: "memory"); } while (0)
#define WVMC(N) asm volatile("s_waitcnt vmcnt(" #N ")" ::: "memory")

// convert one K-quarter of one M-panel: rows [m0,m0+256), cols [256q,256q+256)
// IDEMPOTENT (pure function of x) — concurrent duplicate execution is benign.
__device__ __forceinline__ void conv_quarter(const float* __restrict__ x,
                                             u16* __restrict__ xb,
                                             int m0, int q, int tid) {
    const size_t base = (size_t)m0 * D_DIM + (size_t)q * 256;
#pragma unroll
    for (int p = 0; p < 16; ++p) {
        const int id  = p * 512 + tid;        // 0..8191 chunks of 8
        const int row = id >> 5;              // 0..255
        const int c8  = (id & 31) * 8;        // 0..248
        const size_t off = base + (size_t)row * D_DIM + c8;
        const f32x4 v0 = *(const f32x4*)&x[off];
        const f32x4 v1 = *(const f32x4*)&x[off + 4];
        union { u16 s[8]; uint4 v; } u;
#pragma unroll
        for (int qq = 0; qq < 4; ++qq) { u.s[qq] = f2b(v0[qq]); u.s[4 + qq] = f2b(v1[qq]); }
        *(uint4*)&xb[off] = u.v;
    }
}

// ---------------- kernel 0: input_neurons [8][1024][128] f32 -> Bt2 [1024][1024] bf16
__global__ __launch_bounds__(256)
void prep_b(const float* __restrict__ inn, u16* __restrict__ Bt2) {
    const int idx = (int)blockIdx.x;               // 0..127
    const int n  = idx >> 4;
    const int d0 = (idx & 15) * 64;
    const int r   = threadIdx.x & 127;
    const int hf  = threadIdx.x >> 7;
    const size_t C = (size_t)((r >> 4) * 128 + n * 16 + (r & 15));
#pragma unroll
    for (int g = 0; g < 4; ++g) {
        const int gg = hf * 4 + g;
        union { u16 s[8]; uint4 v; } u;
#pragma unroll
        for (int jj = 0; jj < 8; ++jj)
            u.s[jj] = f2b(inn[((size_t)n * D_DIM + d0 + gg * 8 + jj) * R_DIM + r]);
        *(uint4*)&Bt2[C * D_DIM + d0 + gg * 8] = u.v;
    }
}

// ---------------- kernel 1: MEGA — in-kernel x conversion + 256x256 pipelined GEMM
//                  + fused w-reduction + per-panel Householder epilogue
__global__ __launch_bounds__(512, 2)
void gemm_mega(const float* __restrict__ x, const u16* __restrict__ Bt2,
               const float* __restrict__ iw, const int* __restrict__ pidx,
               const float* __restrict__ pn, u16* __restrict__ xb,
               float* __restrict__ y, int* __restrict__ qf, int* __restrict__ pcnt,
               float* __restrict__ out) {
    __shared__ __align__(16) char smem[131072];   // As 2x32K | Bs 2x32K
    __shared__ int s_ok;
    char* As = smem;
    char* Bs = smem + 65536;

    const int tid  = threadIdx.x;
    const int wid  = tid >> 6, lane = tid & 63;
    const int wm = wid >> 2, wn = wid & 3;
    const int l15 = lane & 15, lq = lane >> 4;

    // XCD-aware bijective swizzle (nwg=256, %8==0). Chunked: siblings (same bx,
    // by=0..3) are consecutive in the remapped id -> same XCD -> shared L2.
    int wg = (int)blockIdx.x;
    wg = (wg & 7) * 32 + (wg >> 3);
    const int by = wg & 3, bx = wg >> 2;
    const int m0 = bx * 256, c0 = by * 256;

    // ---- phase C: convert OWN quarter (rows of panel bx, K [256by,256by+256))
    conv_quarter(x, xb, m0, by, tid);
    WVMC(0);
    __threadfence();
    __syncthreads();
    if (tid == 0)
        __hip_atomic_store(&qf[bx * 4 + by], 1, __ATOMIC_RELEASE, __HIP_MEMORY_SCOPE_AGENT);

#define ENSQ(Q) do { \
    if (tid == 0) { \
        int ok_ = 0; \
        for (int it_ = 0; it_ < 1000 && !ok_; ++it_) { \
            ok_ = __hip_atomic_load(&qf[bx * 4 + (Q)], __ATOMIC_ACQUIRE, __HIP_MEMORY_SCOPE_AGENT); \
            if (!ok_) __builtin_amdgcn_s_sleep(32); \
        } \
        s_ok = ok_; \
    } \
    __syncthreads(); \
    if (!s_ok) { /* fallback: convert it ourselves (idempotent) */ \
        conv_quarter(x, xb, m0, (Q), tid); \
        WVMC(0); __threadfence(); __syncthreads(); \
        if (tid == 0) __hip_atomic_store(&qf[bx * 4 + (Q)], 1, __ATOMIC_RELEASE, __HIP_MEMORY_SCOPE_AGENT); \
        __syncthreads(); \
    } \
} while (0)

    // staging addressing (inverse-swizzled global source, linear LDS dest)
    const int sxor = ((tid & 7) * 16) ^ (((tid >> 3) & 7) << 4);
    const char* gA = (const char*)xb  + ((size_t)(m0 + (tid >> 3))) * 2048 + sxor;
    const char* gB = (const char*)Bt2 + ((size_t)(c0 + (tid >> 3))) * 2048 + sxor;

    // physical K-offset for virtual tile T (rotation start = own quarter)
#define KOF(T) ((size_t)(((4 * by + (T)) & 15) * 128))

#define STA(T1, NB, Q) gload16(gA + (size_t)(Q) * 64 * 2048 + KOF(T1), As + (NB) * 32768 + (Q) * 8192 + tid * 16)
#define STB(T1, NB, C) gload16(gB + (size_t)(C) * 64 * 2048 + KOF(T1), Bs + (NB) * 32768 + (C) * 8192 + tid * 16)

#define RDA(DST, MH, CUR) \
    _Pragma("unroll") for (int i = 0; i < 4; ++i) \
    _Pragma("unroll") for (int kk = 0; kk < 2; ++kk) { \
        const int row = wm * 128 + (MH) * 64 + i * 16 + l15; \
        uint32_t off = (uint32_t)((CUR) * 32768 + row * 128 + kk * 64 + lq * 16); \
        off ^= (uint32_t)((row & 7) << 4); \
        DST[i][kk] = *(const bf16x8*)(As + off); }

#define RDB(NS, CUR) \
    _Pragma("unroll") for (int j = 0; j < 2; ++j) \
    _Pragma("unroll") for (int kk = 0; kk < 2; ++kk) { \
        const int cc = (NS) * 128 + wn * 32 + j * 16 + l15; \
        uint32_t off = (uint32_t)((CUR) * 32768 + cc * 128 + kk * 64 + lq * 16); \
        off ^= (uint32_t)((cc & 7) << 4); \
        b[NS][j][kk] = *(const bf16x8*)(Bs + off); }

#define MM(MH, NS, AF) do { \
    __builtin_amdgcn_s_setprio(1); \
    _Pragma("unroll") for (int i = 0; i < 4; ++i) \
    _Pragma("unroll") for (int j = 0; j < 2; ++j) \
    _Pragma("unroll") for (int kk = 0; kk < 2; ++kk) \
        acc[MH][NS][i][j] = __builtin_amdgcn_mfma_f32_16x16x32_bf16(AF[i][kk], b[NS][j][kk], acc[MH][NS][i][j], 0, 0, 0); \
    __builtin_amdgcn_s_setprio(0); } while (0)

#define TILE(T, CUR, NB) do { \
    const int t1_ = (T) + 1; const bool st_ = (t1_ < 16); \
    bf16x8 a0[4][2], a1[4][2], b[2][2][2]; \
    /* P0 */ \
    RDA(a0, 0, CUR); RDB(0, CUR); \
    if (st_) { STA(t1_, NB, 0); STA(t1_, NB, 2); } \
    SBAR; MM(0, 0, a0); WVMC(4); SBAR; \
    /* P1 */ \
    RDB(1, CUR); \
    if (st_) { STB(t1_, NB, 0); STB(t1_, NB, 1); } \
    SBAR; MM(0, 1, a0); WVMC(4); SBAR; \
    /* P2 */ \
    RDA(a1, 1, CUR); \
    if (st_) { STB(t1_, NB, 2); STB(t1_, NB, 3); } \
    SBAR; MM(1, 0, a1); SBAR; \
    /* P3 */ \
    if (st_) { STA(t1_, NB, 1); STA(t1_, NB, 3); } \
    SBAR; MM(1, 1, a1); WVMC(4); SBAR; \
} while (0)

    f32x4 acc[2][2][4][2] = {};

    // prologue: stage virtual tile 0 (= physical 4*by, own quarter) into buf 0
    STA(0, 0, 0); STA(0, 0, 2);
    STB(0, 0, 0); STB(0, 0, 1);
    STB(0, 0, 2); STB(0, 0, 3);
    STA(0, 0, 1); STA(0, 0, 3);
    WVMC(0); SBAR;

    for (int t = 0; t < 16; t += 2) {
        TILE(t, 0, 1);
        if (((t + 2) & 3) == 0 && (t + 2) < 16)
            ENSQ((by + ((t + 2) >> 2)) & 3);   // quarter of physical tile staged by TILE(t+1)
        TILE(t + 1, 1, 0);
    }
    WVMC(0);   // drain staging before smem reuse

    // ---- epilogue: own = sum_j w[row][2wn+j] * acc; tree-reduce over wn; store y (ws)
    float* P0 = (float*)smem;               // [2][256][17] f32
    float* P1 = (float*)(smem + 34816);
    const float* wrow = iw + (size_t)m0 * NIN;

    float own[2][2][4][4];
#pragma unroll
    for (int mh = 0; mh < 2; ++mh)
#pragma unroll
        for (int i = 0; i < 4; ++i)
#pragma unroll
            for (int e = 0; e < 4; ++e) {
                const int row = wm * 128 + mh * 64 + i * 16 + lq * 4 + e;
                const float w0 = wrow[row * NIN + wn * 2 + 0];
                const float w1 = wrow[row * NIN + wn * 2 + 1];
#pragma unroll
                for (int ns = 0; ns < 2; ++ns)
                    own[mh][ns][i][e] = w0 * acc[mh][ns][i][0][e] + w1 * acc[mh][ns][i][1][e];
            }

#define PIX(NS, ROW) ((NS) * (256 * 17) + (ROW) * 17 + l15)
    SBAR;
    if (wn == 1 || wn == 3) {
        float* P = (wn == 1) ? P0 : P1;
#pragma unroll
        for (int mh = 0; mh < 2; ++mh)
#pragma unroll
            for (int ns = 0; ns < 2; ++ns)
#pragma unroll
                for (int i = 0; i < 4; ++i)
#pragma unroll
                    for (int e = 0; e < 4; ++e) {
                        const int row = wm * 128 + mh * 64 + i * 16 + lq * 4 + e;
                        P[PIX(ns, row)] = own[mh][ns][i][e];
                    }
    }
    SBARL;
    if (wn == 2) {
#pragma unroll
        for (int mh = 0; mh < 2; ++mh)
#pragma unroll
            for (int ns = 0; ns < 2; ++ns)
#pragma unroll
                for (int i = 0; i < 4; ++i)
#pragma unroll
                    for (int e = 0; e < 4; ++e) {
                        const int row = wm * 128 + mh * 64 + i * 16 + lq * 4 + e;
                        P1[PIX(ns, row)] += own[mh][ns][i][e];
                    }
    }
    SBARL;
    if (wn == 0) {
#pragma unroll
        for (int mh = 0; mh < 2; ++mh)
#pragma unroll
            for (int ns = 0; ns < 2; ++ns)
#pragma unroll
                for (int i = 0; i < 4; ++i)
#pragma unroll
                    for (int e = 0; e < 4; ++e) {
                        const int row = wm * 128 + mh * 64 + i * 16 + lq * 4 + e;
                        const float s = own[mh][ns][i][e] + P0[PIX(ns, row)] + P1[PIX(ns, row)];
                        y[(size_t)(m0 + row) * R_DIM + (2 * by + ns) * 16 + l15] = s;
                    }
    }

    // ---- publish this block's y slice; by==0 block runs the Householder chain
    WVMC(0);
    __threadfence();
    __syncthreads();
    if (tid == 0)
        __hip_atomic_fetch_add(&pcnt[bx], 1, __ATOMIC_ACQ_REL, __HIP_MEMORY_SCOPE_AGENT);

    if (by != 0) return;

    if (tid == 0) {
        while (__hip_atomic_load(&pcnt[bx], __ATOMIC_ACQUIRE, __HIP_MEMORY_SCOPE_AGENT) < 4)
            __builtin_amdgcn_s_sleep(8);
        s_ok = 1;
    }
    __syncthreads();

    // house: 512 threads, 8 per token, 64 tokens/pass, 4 passes for the panel
    const int hrow = tid >> 3;
    const int cg   = tid & 7;
    const int hc0  = cg * 16;
#pragma unroll 1
    for (int pass = 0; pass < 4; ++pass) {
        const int tok = m0 + pass * 64 + hrow;
        float yv[16];
#pragma unroll
        for (int q = 0; q < 4; ++q) {
            const f32x4 s = *(const f32x4*)&y[(size_t)tok * R_DIM + hc0 + q * 4];
            yv[q * 4 + 0] = s[0]; yv[q * 4 + 1] = s[1]; yv[q * 4 + 2] = s[2]; yv[q * 4 + 3] = s[3];
        }
        const int4 idx4 = *(const int4*)&pidx[tok * 4];
        const int idxs[4] = { idx4.x, idx4.y, idx4.z, idx4.w };
#pragma unroll
        for (int k = 0; k < 4; ++k) {
            const float* vptr = &pn[(size_t)idxs[k] * R_DIM + hc0];
            float v[16];
#pragma unroll
            for (int q = 0; q < 4; ++q) {
                const f32x4 vv4 = *(const f32x4*)&vptr[q * 4];
                v[q * 4 + 0] = vv4[0]; v[q * 4 + 1] = vv4[1];
                v[q * 4 + 2] = vv4[2]; v[q * 4 + 3] = vv4[3];
            }
            float vy = 0.f, vv = 0.f;
#pragma unroll
            for (int j = 0; j < 16; ++j) { vy += v[j] * yv[j]; vv += v[j] * v[j]; }
#pragma unroll
            for (int o = 1; o < 8; o <<= 1) {
                vy += __shfl_xor(vy, o);
                vv += __shfl_xor(vv, o);
            }
            const float s = 2.0f * vy / (vv + 1e-8f);
#pragma unroll
            for (int j = 0; j < 16; ++j) yv[j] -= s * v[j];
        }
#pragma unroll
        for (int q = 0; q < 4; ++q) {
            f32x4 o; o[0] = yv[q*4+0]; o[1] = yv[q*4+1]; o[2] = yv[q*4+2]; o[3] = yv[q*4+3];
            *(f32x4*)&out[(size_t)tok * R_DIM + hc0 + q * 4] = o;
        }
    }
#undef PIX
#undef TILE
#undef MM
#undef RDB
#undef RDA
#undef STB
#undef STA
#undef KOF
#undef ENSQ
}

extern "C" void kernel_launch(void* const* d_in, const int* in_sizes, int n_in,
                              void* d_out, int out_size, void* d_ws, size_t ws_size,
                              hipStream_t stream) {
    const float* x   = (const float*)d_in[0];   // [4,4096,1024]
    const float* iw  = (const float*)d_in[1];   // [4,4096,8]
    const int*   pix = (const int*)d_in[2];     // [4,4096,4]
    const float* inn = (const float*)d_in[3];   // [8,1024,128]
    const float* pn  = (const float*)d_in[4];   // [32,128]
    float* out = (float*)d_out;                 // [4,4096,128] f32

    u16*   xb   = (u16*)d_ws;                                    // 32 MB
    u16*   Bt2  = (u16*)((char*)d_ws + (size_t)(32 << 20));      // 2 MB
    float* y    = (float*)((char*)d_ws + (size_t)(34 << 20));    // 8 MB
    int*   qf   = (int*)((char*)d_ws + (size_t)(42 << 20));      // 256 ints
    int*   pcnt = qf + 256;                                      // 64 ints

    hipMemsetAsync(qf, 0, 2048, stream);   // reset flags every call (graph-capturable)
    prep_b<<<128, 256, 0, stream>>>(inn, Bt2);
    gemm_mega<<<256, 512, 0, stream>>>(x, Bt2, iw, pix, pn, xb, y, qf, pcnt, out);
}

// Round 7
// 134.955 us; speedup vs baseline: 1.5286x; 1.5286x over previous
//
#include <hip/hip_runtime.h>
#include <hip/hip_bf16.h>
#include <stdint.h>

#define D_DIM 1024
#define R_DIM 128
#define NIN   8
#define M_TOT 16384

typedef unsigned short u16;
typedef __attribute__((ext_vector_type(4))) float f32x4;
typedef __attribute__((ext_vector_type(8))) __bf16 bf16x8;

__device__ __forceinline__ u16 f2b(float f) {
    union { float f; uint32_t u; } v; v.f = f;
    uint32_t r = (v.u + 0x7FFFu + ((v.u >> 16) & 1u)) >> 16;
    return (u16)r;
}

__device__ __forceinline__ void gload16(const void* g, void* l) {
    __builtin_amdgcn_global_load_lds(
        (const __attribute__((address_space(1))) uint32_t*)g,
        (__attribute__((address_space(3))) uint32_t*)l, 16, 0, 0);
}

#define SBAR  do { asm volatile("" ::: "memory"); __builtin_amdgcn_s_barrier(); asm volatile("" ::: "memory"); } while (0)
#define SBARL do { asm volatile("s_waitcnt lgkmcnt(0)" ::: "memory"); __builtin_amdgcn_s_barrier(); asm volatile("" ::: "memory"); } while (0)
#define WVMC(N) asm volatile("s_waitcnt vmcnt(" #N ")" ::: "memory")

// ---------------- kernel 0: fused prep — x f32->bf16 (blocks 0..8191) + Bt2 build (blocks 8192..8319)
__global__ __launch_bounds__(256)
void prep(const float* __restrict__ x, u16* __restrict__ xb,
          const float* __restrict__ inn, u16* __restrict__ Bt2) {
    if (blockIdx.x < 8192) {
        const size_t i = ((size_t)blockIdx.x * 256 + threadIdx.x) * 8;
        const f32x4 v0 = *(const f32x4*)&x[i];
        const f32x4 v1 = *(const f32x4*)&x[i + 4];
        union { u16 s[8]; uint4 v; } u;
#pragma unroll
        for (int q = 0; q < 4; ++q) { u.s[q] = f2b(v0[q]); u.s[4 + q] = f2b(v1[q]); }
        *(uint4*)&xb[i] = u.v;
    } else {
        const int idx = (int)blockIdx.x - 8192;        // 0..127
        const int n  = idx >> 4;                        // 0..7
        const int d0 = (idx & 15) * 64;
        const int r   = threadIdx.x & 127;
        const int hf  = threadIdx.x >> 7;               // 0..1
        const size_t C = (size_t)((r >> 4) * 128 + n * 16 + (r & 15));
#pragma unroll
        for (int g = 0; g < 4; ++g) {
            const int gg = hf * 4 + g;
            union { u16 s[8]; uint4 v; } u;
#pragma unroll
            for (int jj = 0; jj < 8; ++jj)
                u.s[jj] = f2b(inn[((size_t)n * D_DIM + d0 + gg * 8 + jj) * R_DIM + r]);
            *(uint4*)&Bt2[C * D_DIM + d0 + gg * 8] = u.v;
        }
    }
}

// ---------------- kernel 1: 256x256 pipelined GEMM + fused w-reduction + per-panel
//                  completion sync + inline Householder tail (no separate house launch)
__global__ __launch_bounds__(512, 2)
void gemm8(const u16* __restrict__ xb, const u16* __restrict__ Bt2,
           const float* __restrict__ iw, const int* __restrict__ pidx,
           const float* __restrict__ pn, float* __restrict__ y,
           int* __restrict__ pcnt, float* __restrict__ out) {
    __shared__ __align__(16) char smem[131072];   // As 2x32K | Bs 2x32K
    char* As = smem;
    char* Bs = smem + 65536;

    const int tid  = threadIdx.x;
    const int wid  = tid >> 6, lane = tid & 63;
    const int wm = wid >> 2, wn = wid & 3;
    const int l15 = lane & 15, lq = lane >> 4;

    // XCD-aware bijective swizzle (nwg=256, %8==0). Chunked: by-siblings of a
    // panel land on the same XCD (performance heuristic; correctness relies on
    // agent-scope atomics/fences below, not on this mapping).
    int wg = (int)blockIdx.x;
    wg = (wg & 7) * 32 + (wg >> 3);
    const int by = wg & 3, bx = wg >> 2;
    const int m0 = bx * 256, c0 = by * 256;

    // staging addressing (inverse-swizzled global source, linear LDS dest)
    const int sxor = ((tid & 7) * 16) ^ (((tid >> 3) & 7) << 4);
    const char* gA = (const char*)xb  + ((size_t)(m0 + (tid >> 3))) * 2048 + sxor;
    const char* gB = (const char*)Bt2 + ((size_t)(c0 + (tid >> 3))) * 2048 + sxor;

#define STA(T1, NB, Q) gload16(gA + (size_t)(Q) * 64 * 2048 + (size_t)(T1) * 128, As + (NB) * 32768 + (Q) * 8192 + tid * 16)
#define STB(T1, NB, C) gload16(gB + (size_t)(C) * 64 * 2048 + (size_t)(T1) * 128, Bs + (NB) * 32768 + (C) * 8192 + tid * 16)

#define RDA(DST, MH, CUR) \
    _Pragma("unroll") for (int i = 0; i < 4; ++i) \
    _Pragma("unroll") for (int kk = 0; kk < 2; ++kk) { \
        const int row = wm * 128 + (MH) * 64 + i * 16 + l15; \
        uint32_t off = (uint32_t)((CUR) * 32768 + row * 128 + kk * 64 + lq * 16); \
        off ^= (uint32_t)((row & 7) << 4); \
        DST[i][kk] = *(const bf16x8*)(As + off); }

#define RDB(NS, CUR) \
    _Pragma("unroll") for (int j = 0; j < 2; ++j) \
    _Pragma("unroll") for (int kk = 0; kk < 2; ++kk) { \
        const int cc = (NS) * 128 + wn * 32 + j * 16 + l15; \
        uint32_t off = (uint32_t)((CUR) * 32768 + cc * 128 + kk * 64 + lq * 16); \
        off ^= (uint32_t)((cc & 7) << 4); \
        b[NS][j][kk] = *(const bf16x8*)(Bs + off); }

#define MM(MH, NS, AF) do { \
    __builtin_amdgcn_s_setprio(1); \
    _Pragma("unroll") for (int i = 0; i < 4; ++i) \
    _Pragma("unroll") for (int j = 0; j < 2; ++j) \
    _Pragma("unroll") for (int kk = 0; kk < 2; ++kk) \
        acc[MH][NS][i][j] = __builtin_amdgcn_mfma_f32_16x16x32_bf16(AF[i][kk], b[NS][j][kk], acc[MH][NS][i][j], 0, 0, 0); \
    __builtin_amdgcn_s_setprio(0); } while (0)

#define TILE(T, CUR, NB) do { \
    const int t1_ = (T) + 1; const bool st_ = (t1_ < 16); \
    bf16x8 a0[4][2], a1[4][2], b[2][2][2]; \
    /* P0 */ \
    RDA(a0, 0, CUR); RDB(0, CUR); \
    if (st_) { STA(t1_, NB, 0); STA(t1_, NB, 2); } \
    SBAR; MM(0, 0, a0); WVMC(4); SBAR; \
    /* P1 */ \
    RDB(1, CUR); \
    if (st_) { STB(t1_, NB, 0); STB(t1_, NB, 1); } \
    SBAR; MM(0, 1, a0); WVMC(4); SBAR; \
    /* P2 */ \
    RDA(a1, 1, CUR); \
    if (st_) { STB(t1_, NB, 2); STB(t1_, NB, 3); } \
    SBAR; MM(1, 0, a1); SBAR; \
    /* P3 */ \
    if (st_) { STA(t1_, NB, 1); STA(t1_, NB, 3); } \
    SBAR; MM(1, 1, a1); WVMC(4); SBAR; \
} while (0)

    f32x4 acc[2][2][4][2] = {};

    // prologue: stage tile 0 into buf 0, order A02, B01, B23, A13
    STA(0, 0, 0); STA(0, 0, 2);
    STB(0, 0, 0); STB(0, 0, 1);
    STB(0, 0, 2); STB(0, 0, 3);
    STA(0, 0, 1); STA(0, 0, 3);
    WVMC(0); SBAR;

    for (int t = 0; t < 16; t += 2) {
        TILE(t, 0, 1);
        TILE(t + 1, 1, 0);
    }
    WVMC(0);   // drain staging before smem reuse

    // ---- epilogue: own = sum_j w[row][2wn+j] * acc; tree-reduce over wn; store y (ws)
    float* P0 = (float*)smem;               // [2][256][17] f32
    float* P1 = (float*)(smem + 34816);
    const float* wrow = iw + (size_t)m0 * NIN;

    float own[2][2][4][4];
#pragma unroll
    for (int mh = 0; mh < 2; ++mh)
#pragma unroll
        for (int i = 0; i < 4; ++i)
#pragma unroll
            for (int e = 0; e < 4; ++e) {
                const int row = wm * 128 + mh * 64 + i * 16 + lq * 4 + e;
                const float w0 = wrow[row * NIN + wn * 2 + 0];
                const float w1 = wrow[row * NIN + wn * 2 + 1];
#pragma unroll
                for (int ns = 0; ns < 2; ++ns)
                    own[mh][ns][i][e] = w0 * acc[mh][ns][i][0][e] + w1 * acc[mh][ns][i][1][e];
            }

#define PIX(NS, ROW) ((NS) * (256 * 17) + (ROW) * 17 + l15)
    SBAR;   // all waves past K-loop before smem overwrite
    if (wn == 1 || wn == 3) {
        float* P = (wn == 1) ? P0 : P1;
#pragma unroll
        for (int mh = 0; mh < 2; ++mh)
#pragma unroll
            for (int ns = 0; ns < 2; ++ns)
#pragma unroll
                for (int i = 0; i < 4; ++i)
#pragma unroll
                    for (int e = 0; e < 4; ++e) {
                        const int row = wm * 128 + mh * 64 + i * 16 + lq * 4 + e;
                        P[PIX(ns, row)] = own[mh][ns][i][e];
                    }
    }
    SBARL;
    if (wn == 2) {
#pragma unroll
        for (int mh = 0; mh < 2; ++mh)
#pragma unroll
            for (int ns = 0; ns < 2; ++ns)
#pragma unroll
                for (int i = 0; i < 4; ++i)
#pragma unroll
                    for (int e = 0; e < 4; ++e) {
                        const int row = wm * 128 + mh * 64 + i * 16 + lq * 4 + e;
                        P1[PIX(ns, row)] += own[mh][ns][i][e];
                    }
    }
    SBARL;
    if (wn == 0) {
#pragma unroll
        for (int mh = 0; mh < 2; ++mh)
#pragma unroll
            for (int ns = 0; ns < 2; ++ns)
#pragma unroll
                for (int i = 0; i < 4; ++i)
#pragma unroll
                    for (int e = 0; e < 4; ++e) {
                        const int row = wm * 128 + mh * 64 + i * 16 + lq * 4 + e;
                        const float s = own[mh][ns][i][e] + P0[PIX(ns, row)] + P1[PIX(ns, row)];
                        y[(size_t)(m0 + row) * R_DIM + (2 * by + ns) * 16 + l15] = s;
                    }
    }

    // ---- per-panel completion: publish y slice, wait for the 4 by-siblings
    __threadfence();
    __syncthreads();
    if (tid == 0)
        __hip_atomic_fetch_add(&pcnt[bx], 1, __ATOMIC_ACQ_REL, __HIP_MEMORY_SCOPE_AGENT);

    if (tid == 0) {
        while (__hip_atomic_load(&pcnt[bx], __ATOMIC_ACQUIRE, __HIP_MEMORY_SCOPE_AGENT) < 4)
            __builtin_amdgcn_s_sleep(2);
    }
    __syncthreads();
    // per-thread acquire so every lane's cache view is ordered after the count
    (void)__hip_atomic_load(&pcnt[bx], __ATOMIC_ACQUIRE, __HIP_MEMORY_SCOPE_AGENT);

    // ---- inline house: this block handles 64 tokens of its panel (one pass)
    const int hrow = tid >> 3;          // 0..63
    const int cg   = tid & 7;
    const int hc0  = cg * 16;
    const int tok  = m0 + by * 64 + hrow;

    float yv[16];
#pragma unroll
    for (int q = 0; q < 4; ++q) {
        const f32x4 s = *(const f32x4*)&y[(size_t)tok * R_DIM + hc0 + q * 4];
        yv[q * 4 + 0] = s[0]; yv[q * 4 + 1] = s[1]; yv[q * 4 + 2] = s[2]; yv[q * 4 + 3] = s[3];
    }
    const int4 idx4 = *(const int4*)&pidx[tok * 4];
    const int idxs[4] = { idx4.x, idx4.y, idx4.z, idx4.w };
#pragma unroll
    for (int k = 0; k < 4; ++k) {
        const float* vptr = &pn[(size_t)idxs[k] * R_DIM + hc0];
        float v[16];
#pragma unroll
        for (int q = 0; q < 4; ++q) {
            const f32x4 vv4 = *(const f32x4*)&vptr[q * 4];
            v[q * 4 + 0] = vv4[0]; v[q * 4 + 1] = vv4[1];
            v[q * 4 + 2] = vv4[2]; v[q * 4 + 3] = vv4[3];
        }
        float vy = 0.f, vv = 0.f;
#pragma unroll
        for (int j = 0; j < 16; ++j) { vy += v[j] * yv[j]; vv += v[j] * v[j]; }
#pragma unroll
        for (int o = 1; o < 8; o <<= 1) {
            vy += __shfl_xor(vy, o);
            vv += __shfl_xor(vv, o);
        }
        const float s = 2.0f * vy / (vv + 1e-8f);
#pragma unroll
        for (int j = 0; j < 16; ++j) yv[j] -= s * v[j];
    }
#pragma unroll
    for (int q = 0; q < 4; ++q) {
        f32x4 o; o[0] = yv[q*4+0]; o[1] = yv[q*4+1]; o[2] = yv[q*4+2]; o[3] = yv[q*4+3];
        *(f32x4*)&out[(size_t)tok * R_DIM + hc0 + q * 4] = o;
    }
#undef PIX
#undef TILE
#undef MM
#undef RDB
#undef RDA
#undef STB
#undef STA
}

extern "C" void kernel_launch(void* const* d_in, const int* in_sizes, int n_in,
                              void* d_out, int out_size, void* d_ws, size_t ws_size,
                              hipStream_t stream) {
    const float* x   = (const float*)d_in[0];   // [4,4096,1024]
    const float* iw  = (const float*)d_in[1];   // [4,4096,8]
    const int*   pix = (const int*)d_in[2];     // [4,4096,4]
    const float* inn = (const float*)d_in[3];   // [8,1024,128]
    const float* pn  = (const float*)d_in[4];   // [32,128]
    float* out = (float*)d_out;                 // [4,4096,128] f32

    u16*   xb   = (u16*)d_ws;                                    // 32 MB
    u16*   Bt2  = (u16*)((char*)d_ws + (size_t)(32 << 20));      // 2 MB
    float* y    = (float*)((char*)d_ws + (size_t)(34 << 20));    // 8 MB
    int*   pcnt = (int*)((char*)d_ws + (size_t)(42 << 20));      // 64 ints

    hipMemsetAsync(pcnt, 0, 1024, stream);   // reset per-panel counters (graph-capturable)
    prep<<<8320, 256, 0, stream>>>(x, xb, inn, Bt2);
    gemm8<<<256, 512, 0, stream>>>(xb, Bt2, iw, pix, pn, y, pcnt, out);
}

// Round 8
// 129.114 us; speedup vs baseline: 1.5977x; 1.0452x over previous
//
#include <hip/hip_runtime.h>
#include <hip/hip_bf16.h>
#include <stdint.h>

#define D_DIM 1024
#define R_DIM 128
#define NIN   8
#define M_TOT 16384

typedef unsigned short u16;
typedef __attribute__((ext_vector_type(4))) float f32x4;
typedef __attribute__((ext_vector_type(8))) __bf16 bf16x8;

__device__ __forceinline__ u16 f2b(float f) {
    union { float f; uint32_t u; } v; v.f = f;
    uint32_t r = (v.u + 0x7FFFu + ((v.u >> 16) & 1u)) >> 16;
    return (u16)r;
}

__device__ __forceinline__ void gload16(const void* g, void* l) {
    __builtin_amdgcn_global_load_lds(
        (const __attribute__((address_space(1))) uint32_t*)g,
        (__attribute__((address_space(3))) uint32_t*)l, 16, 0, 0);
}

#define SBAR  do { asm volatile("" ::: "memory"); __builtin_amdgcn_s_barrier(); asm volatile("" ::: "memory"); } while (0)
#define SBARL do { asm volatile("s_waitcnt lgkmcnt(0)" ::: "memory"); __builtin_amdgcn_s_barrier(); asm volatile("" ::: "memory"); } while (0)
#define WVMC(N) asm volatile("s_waitcnt vmcnt(" #N ")" ::: "memory")

// ---------------- kernel 0: fused prep — x f32->bf16 (blocks 0..8191) + Bt2 build (blocks 8192..8319)
__global__ __launch_bounds__(256)
void prep(const float* __restrict__ x, u16* __restrict__ xb,
          const float* __restrict__ inn, u16* __restrict__ Bt2) {
    if (blockIdx.x < 8192) {
        const size_t i = ((size_t)blockIdx.x * 256 + threadIdx.x) * 8;
        const f32x4 v0 = *(const f32x4*)&x[i];
        const f32x4 v1 = *(const f32x4*)&x[i + 4];
        union { u16 s[8]; uint4 v; } u;
#pragma unroll
        for (int q = 0; q < 4; ++q) { u.s[q] = f2b(v0[q]); u.s[4 + q] = f2b(v1[q]); }
        *(uint4*)&xb[i] = u.v;
    } else {
        const int idx = (int)blockIdx.x - 8192;        // 0..127
        const int n  = idx >> 4;                        // 0..7
        const int d0 = (idx & 15) * 64;
        const int r   = threadIdx.x & 127;
        const int hf  = threadIdx.x >> 7;               // 0..1
        const size_t C = (size_t)((r >> 4) * 128 + n * 16 + (r & 15));
#pragma unroll
        for (int g = 0; g < 4; ++g) {
            const int gg = hf * 4 + g;
            union { u16 s[8]; uint4 v; } u;
#pragma unroll
            for (int jj = 0; jj < 8; ++jj)
                u.s[jj] = f2b(inn[((size_t)n * D_DIM + d0 + gg * 8 + jj) * R_DIM + r]);
            *(uint4*)&Bt2[C * D_DIM + d0 + gg * 8] = u.v;
        }
    }
}

// ---------------- kernel 1: 256x256 pipelined GEMM + fused w-reduction + LAST-ARRIVER
//                  Householder tail (no waiting: non-last siblings exit immediately)
__global__ __launch_bounds__(512, 2)
void gemm8(const u16* __restrict__ xb, const u16* __restrict__ Bt2,
           const float* __restrict__ iw, const int* __restrict__ pidx,
           const float* __restrict__ pn, float* __restrict__ y,
           int* __restrict__ pcnt, float* __restrict__ out) {
    __shared__ __align__(16) char smem[131072];   // As 2x32K | Bs 2x32K
    char* As = smem;
    char* Bs = smem + 65536;

    const int tid  = threadIdx.x;
    const int wid  = tid >> 6, lane = tid & 63;
    const int wm = wid >> 2, wn = wid & 3;
    const int l15 = lane & 15, lq = lane >> 4;

    // XCD-aware bijective swizzle (nwg=256, %8==0). Chunked: by-siblings of a
    // panel land on the same XCD (perf heuristic; correctness relies on
    // agent-scope atomics/fences below, not on this mapping).
    int wg = (int)blockIdx.x;
    wg = (wg & 7) * 32 + (wg >> 3);
    const int by = wg & 3, bx = wg >> 2;
    const int m0 = bx * 256, c0 = by * 256;

    // staging addressing (inverse-swizzled global source, linear LDS dest)
    const int sxor = ((tid & 7) * 16) ^ (((tid >> 3) & 7) << 4);
    const char* gA = (const char*)xb  + ((size_t)(m0 + (tid >> 3))) * 2048 + sxor;
    const char* gB = (const char*)Bt2 + ((size_t)(c0 + (tid >> 3))) * 2048 + sxor;

#define STA(T1, NB, Q) gload16(gA + (size_t)(Q) * 64 * 2048 + (size_t)(T1) * 128, As + (NB) * 32768 + (Q) * 8192 + tid * 16)
#define STB(T1, NB, C) gload16(gB + (size_t)(C) * 64 * 2048 + (size_t)(T1) * 128, Bs + (NB) * 32768 + (C) * 8192 + tid * 16)

#define RDA(DST, MH, CUR) \
    _Pragma("unroll") for (int i = 0; i < 4; ++i) \
    _Pragma("unroll") for (int kk = 0; kk < 2; ++kk) { \
        const int row = wm * 128 + (MH) * 64 + i * 16 + l15; \
        uint32_t off = (uint32_t)((CUR) * 32768 + row * 128 + kk * 64 + lq * 16); \
        off ^= (uint32_t)((row & 7) << 4); \
        DST[i][kk] = *(const bf16x8*)(As + off); }

#define RDB(NS, CUR) \
    _Pragma("unroll") for (int j = 0; j < 2; ++j) \
    _Pragma("unroll") for (int kk = 0; kk < 2; ++kk) { \
        const int cc = (NS) * 128 + wn * 32 + j * 16 + l15; \
        uint32_t off = (uint32_t)((CUR) * 32768 + cc * 128 + kk * 64 + lq * 16); \
        off ^= (uint32_t)((cc & 7) << 4); \
        b[NS][j][kk] = *(const bf16x8*)(Bs + off); }

#define MM(MH, NS, AF) do { \
    __builtin_amdgcn_s_setprio(1); \
    _Pragma("unroll") for (int i = 0; i < 4; ++i) \
    _Pragma("unroll") for (int j = 0; j < 2; ++j) \
    _Pragma("unroll") for (int kk = 0; kk < 2; ++kk) \
        acc[MH][NS][i][j] = __builtin_amdgcn_mfma_f32_16x16x32_bf16(AF[i][kk], b[NS][j][kk], acc[MH][NS][i][j], 0, 0, 0); \
    __builtin_amdgcn_s_setprio(0); } while (0)

#define TILE(T, CUR, NB) do { \
    const int t1_ = (T) + 1; const bool st_ = (t1_ < 16); \
    bf16x8 a0[4][2], a1[4][2], b[2][2][2]; \
    /* P0 */ \
    RDA(a0, 0, CUR); RDB(0, CUR); \
    if (st_) { STA(t1_, NB, 0); STA(t1_, NB, 2); } \
    SBAR; MM(0, 0, a0); WVMC(4); SBAR; \
    /* P1 */ \
    RDB(1, CUR); \
    if (st_) { STB(t1_, NB, 0); STB(t1_, NB, 1); } \
    SBAR; MM(0, 1, a0); WVMC(4); SBAR; \
    /* P2 */ \
    RDA(a1, 1, CUR); \
    if (st_) { STB(t1_, NB, 2); STB(t1_, NB, 3); } \
    SBAR; MM(1, 0, a1); SBAR; \
    /* P3 */ \
    if (st_) { STA(t1_, NB, 1); STA(t1_, NB, 3); } \
    SBAR; MM(1, 1, a1); WVMC(4); SBAR; \
} while (0)

    f32x4 acc[2][2][4][2] = {};

    // prologue: stage tile 0 into buf 0, order A02, B01, B23, A13
    STA(0, 0, 0); STA(0, 0, 2);
    STB(0, 0, 0); STB(0, 0, 1);
    STB(0, 0, 2); STB(0, 0, 3);
    STA(0, 0, 1); STA(0, 0, 3);
    WVMC(0); SBAR;

    for (int t = 0; t < 16; t += 2) {
        TILE(t, 0, 1);
        TILE(t + 1, 1, 0);
    }
    WVMC(0);   // drain staging before smem reuse

    // ---- epilogue: own = sum_j w[row][2wn+j] * acc; tree-reduce over wn; store y (ws)
    float* P0 = (float*)smem;               // [2][256][17] f32
    float* P1 = (float*)(smem + 34816);
    const float* wrow = iw + (size_t)m0 * NIN;

    float own[2][2][4][4];
#pragma unroll
    for (int mh = 0; mh < 2; ++mh)
#pragma unroll
        for (int i = 0; i < 4; ++i)
#pragma unroll
            for (int e = 0; e < 4; ++e) {
                const int row = wm * 128 + mh * 64 + i * 16 + lq * 4 + e;
                const float w0 = wrow[row * NIN + wn * 2 + 0];
                const float w1 = wrow[row * NIN + wn * 2 + 1];
#pragma unroll
                for (int ns = 0; ns < 2; ++ns)
                    own[mh][ns][i][e] = w0 * acc[mh][ns][i][0][e] + w1 * acc[mh][ns][i][1][e];
            }

#define PIX(NS, ROW) ((NS) * (256 * 17) + (ROW) * 17 + l15)
    SBAR;   // all waves past K-loop before smem overwrite
    if (wn == 1 || wn == 3) {
        float* P = (wn == 1) ? P0 : P1;
#pragma unroll
        for (int mh = 0; mh < 2; ++mh)
#pragma unroll
            for (int ns = 0; ns < 2; ++ns)
#pragma unroll
                for (int i = 0; i < 4; ++i)
#pragma unroll
                    for (int e = 0; e < 4; ++e) {
                        const int row = wm * 128 + mh * 64 + i * 16 + lq * 4 + e;
                        P[PIX(ns, row)] = own[mh][ns][i][e];
                    }
    }
    SBARL;
    if (wn == 2) {
#pragma unroll
        for (int mh = 0; mh < 2; ++mh)
#pragma unroll
            for (int ns = 0; ns < 2; ++ns)
#pragma unroll
                for (int i = 0; i < 4; ++i)
#pragma unroll
                    for (int e = 0; e < 4; ++e) {
                        const int row = wm * 128 + mh * 64 + i * 16 + lq * 4 + e;
                        P1[PIX(ns, row)] += own[mh][ns][i][e];
                    }
    }
    SBARL;
    if (wn == 0) {
#pragma unroll
        for (int mh = 0; mh < 2; ++mh)
#pragma unroll
            for (int ns = 0; ns < 2; ++ns)
#pragma unroll
                for (int i = 0; i < 4; ++i)
#pragma unroll
                    for (int e = 0; e < 4; ++e) {
                        const int row = wm * 128 + mh * 64 + i * 16 + lq * 4 + e;
                        const float s = own[mh][ns][i][e] + P0[PIX(ns, row)] + P1[PIX(ns, row)];
                        y[(size_t)(m0 + row) * R_DIM + (2 * by + ns) * 16 + l15] = s;
                    }
    }

    // ---- last-arriver tail: NO waiting. Publish y slice; the 4th sibling to
    // arrive houses the whole panel; the other 3 exit immediately.
    __threadfence();          // release this thread's y stores (agent scope)
    SBAR;                     // all waves of this block have fenced
    volatile int* s_last = (volatile int*)(smem + 131008);
    if (tid == 0) {
        const int old = __hip_atomic_fetch_add(&pcnt[bx], 1, __ATOMIC_ACQ_REL, __HIP_MEMORY_SCOPE_AGENT);
        *s_last = (old == 3);
    }
    SBARL;
    if (!*s_last) return;
    // acquire: order this block's y reads after the siblings' releases
    (void)__hip_atomic_load(&pcnt[bx], __ATOMIC_ACQUIRE, __HIP_MEMORY_SCOPE_AGENT);

    // house the full panel: 256 tokens, 8 threads/token, 4 passes
    const int hrow = tid >> 3;          // 0..63
    const int cg   = tid & 7;
    const int hc0  = cg * 16;
#pragma unroll 1
    for (int pass = 0; pass < 4; ++pass) {
        const int tok = m0 + pass * 64 + hrow;
        float yv[16];
#pragma unroll
        for (int q = 0; q < 4; ++q) {
            const f32x4 s = *(const f32x4*)&y[(size_t)tok * R_DIM + hc0 + q * 4];
            yv[q * 4 + 0] = s[0]; yv[q * 4 + 1] = s[1]; yv[q * 4 + 2] = s[2]; yv[q * 4 + 3] = s[3];
        }
        const int4 idx4 = *(const int4*)&pidx[tok * 4];
        const int idxs[4] = { idx4.x, idx4.y, idx4.z, idx4.w };
#pragma unroll
        for (int k = 0; k < 4; ++k) {
            const float* vptr = &pn[(size_t)idxs[k] * R_DIM + hc0];
            float v[16];
#pragma unroll
            for (int q = 0; q < 4; ++q) {
                const f32x4 vv4 = *(const f32x4*)&vptr[q * 4];
                v[q * 4 + 0] = vv4[0]; v[q * 4 + 1] = vv4[1];
                v[q * 4 + 2] = vv4[2]; v[q * 4 + 3] = vv4[3];
            }
            float vy = 0.f, vv = 0.f;
#pragma unroll
            for (int j = 0; j < 16; ++j) { vy += v[j] * yv[j]; vv += v[j] * v[j]; }
#pragma unroll
            for (int o = 1; o < 8; o <<= 1) {
                vy += __shfl_xor(vy, o);
                vv += __shfl_xor(vv, o);
            }
            const float s = 2.0f * vy / (vv + 1e-8f);
#pragma unroll
            for (int j = 0; j < 16; ++j) yv[j] -= s * v[j];
        }
#pragma unroll
        for (int q = 0; q < 4; ++q) {
            f32x4 o; o[0] = yv[q*4+0]; o[1] = yv[q*4+1]; o[2] = yv[q*4+2]; o[3] = yv[q*4+3];
            *(f32x4*)&out[(size_t)tok * R_DIM + hc0 + q * 4] = o;
        }
    }
#undef PIX
#undef TILE
#undef MM
#undef RDB
#undef RDA
#undef STB
#undef STA
}

extern "C" void kernel_launch(void* const* d_in, const int* in_sizes, int n_in,
                              void* d_out, int out_size, void* d_ws, size_t ws_size,
                              hipStream_t stream) {
    const float* x   = (const float*)d_in[0];   // [4,4096,1024]
    const float* iw  = (const float*)d_in[1];   // [4,4096,8]
    const int*   pix = (const int*)d_in[2];     // [4,4096,4]
    const float* inn = (const float*)d_in[3];   // [8,1024,128]
    const float* pn  = (const float*)d_in[4];   // [32,128]
    float* out = (float*)d_out;                 // [4,4096,128] f32

    u16*   xb   = (u16*)d_ws;                                    // 32 MB
    u16*   Bt2  = (u16*)((char*)d_ws + (size_t)(32 << 20));      // 2 MB
    float* y    = (float*)((char*)d_ws + (size_t)(34 << 20));    // 8 MB
    int*   pcnt = (int*)((char*)d_ws + (size_t)(42 << 20));      // 64 ints

    hipMemsetAsync(pcnt, 0, 1024, stream);   // reset per-panel counters (graph-capturable)
    prep<<<8320, 256, 0, stream>>>(x, xb, inn, Bt2);
    gemm8<<<256, 512, 0, stream>>>(xb, Bt2, iw, pix, pn, y, pcnt, out);
}

// Round 9
// 65.865 us; speedup vs baseline: 3.1320x; 1.9603x over previous
//
#include <hip/hip_runtime.h>
#include <hip/hip_bf16.h>
#include <stdint.h>

#define D_DIM 1024
#define R_DIM 128
#define NIN   8
#define M_TOT 16384

typedef unsigned short u16;
typedef __attribute__((ext_vector_type(4))) float f32x4;
typedef __attribute__((ext_vector_type(8))) __bf16 bf16x8;

__device__ __forceinline__ u16 f2b(float f) {
    union { float f; uint32_t u; } v; v.f = f;
    uint32_t r = (v.u + 0x7FFFu + ((v.u >> 16) & 1u)) >> 16;
    return (u16)r;
}

__device__ __forceinline__ void gload16(const void* g, void* l) {
    __builtin_amdgcn_global_load_lds(
        (const __attribute__((address_space(1))) uint32_t*)g,
        (__attribute__((address_space(3))) uint32_t*)l, 16, 0, 0);
}

#define SBAR  do { asm volatile("" ::: "memory"); __builtin_amdgcn_s_barrier(); asm volatile("" ::: "memory"); } while (0)
#define SBARL do { asm volatile("s_waitcnt lgkmcnt(0)" ::: "memory"); __builtin_amdgcn_s_barrier(); asm volatile("" ::: "memory"); } while (0)
#define WVMC(N) asm volatile("s_waitcnt vmcnt(" #N ")" ::: "memory")

// ---------------- kernel 0: fused prep — x f32->bf16 (blocks 0..8191) + Bt2 build (blocks 8192..8319)
__global__ __launch_bounds__(256)
void prep(const float* __restrict__ x, u16* __restrict__ xb,
          const float* __restrict__ inn, u16* __restrict__ Bt2) {
    if (blockIdx.x < 8192) {
        const size_t i = ((size_t)blockIdx.x * 256 + threadIdx.x) * 8;
        const f32x4 v0 = *(const f32x4*)&x[i];
        const f32x4 v1 = *(const f32x4*)&x[i + 4];
        union { u16 s[8]; uint4 v; } u;
#pragma unroll
        for (int q = 0; q < 4; ++q) { u.s[q] = f2b(v0[q]); u.s[4 + q] = f2b(v1[q]); }
        *(uint4*)&xb[i] = u.v;
    } else {
        const int idx = (int)blockIdx.x - 8192;        // 0..127
        const int n  = idx >> 4;                        // 0..7
        const int d0 = (idx & 15) * 64;
        const int r   = threadIdx.x & 127;
        const int hf  = threadIdx.x >> 7;               // 0..1
        const size_t C = (size_t)((r >> 4) * 128 + n * 16 + (r & 15));
#pragma unroll
        for (int g = 0; g < 4; ++g) {
            const int gg = hf * 4 + g;
            union { u16 s[8]; uint4 v; } u;
#pragma unroll
            for (int jj = 0; jj < 8; ++jj)
                u.s[jj] = f2b(inn[((size_t)n * D_DIM + d0 + gg * 8 + jj) * R_DIM + r]);
            *(uint4*)&Bt2[C * D_DIM + d0 + gg * 8] = u.v;
        }
    }
}

// ---------------- kernel 1: 256x256 pipelined GEMM + fused w-reduction (r5-proven)
__global__ __launch_bounds__(512, 2)
void gemm8(const u16* __restrict__ xb, const u16* __restrict__ Bt2,
           const float* __restrict__ iw, float* __restrict__ y) {
    __shared__ __align__(16) char smem[131072];   // As 2x32K | Bs 2x32K
    char* As = smem;
    char* Bs = smem + 65536;

    const int tid  = threadIdx.x;
    const int wid  = tid >> 6, lane = tid & 63;
    const int wm = wid >> 2, wn = wid & 3;
    const int l15 = lane & 15, lq = lane >> 4;

    // XCD-aware bijective swizzle (nwg=256, %8==0)
    int wg = (int)blockIdx.x;
    wg = (wg & 7) * 32 + (wg >> 3);
    const int by = wg & 3, bx = wg >> 2;
    const int m0 = bx * 256, c0 = by * 256;

    // staging addressing (inverse-swizzled global source, linear LDS dest)
    const int sxor = ((tid & 7) * 16) ^ (((tid >> 3) & 7) << 4);
    const char* gA = (const char*)xb  + ((size_t)(m0 + (tid >> 3))) * 2048 + sxor;
    const char* gB = (const char*)Bt2 + ((size_t)(c0 + (tid >> 3))) * 2048 + sxor;

#define STA(T1, NB, Q) gload16(gA + (size_t)(Q) * 64 * 2048 + (size_t)(T1) * 128, As + (NB) * 32768 + (Q) * 8192 + tid * 16)
#define STB(T1, NB, C) gload16(gB + (size_t)(C) * 64 * 2048 + (size_t)(T1) * 128, Bs + (NB) * 32768 + (C) * 8192 + tid * 16)

#define RDA(DST, MH, CUR) \
    _Pragma("unroll") for (int i = 0; i < 4; ++i) \
    _Pragma("unroll") for (int kk = 0; kk < 2; ++kk) { \
        const int row = wm * 128 + (MH) * 64 + i * 16 + l15; \
        uint32_t off = (uint32_t)((CUR) * 32768 + row * 128 + kk * 64 + lq * 16); \
        off ^= (uint32_t)((row & 7) << 4); \
        DST[i][kk] = *(const bf16x8*)(As + off); }

#define RDB(NS, CUR) \
    _Pragma("unroll") for (int j = 0; j < 2; ++j) \
    _Pragma("unroll") for (int kk = 0; kk < 2; ++kk) { \
        const int cc = (NS) * 128 + wn * 32 + j * 16 + l15; \
        uint32_t off = (uint32_t)((CUR) * 32768 + cc * 128 + kk * 64 + lq * 16); \
        off ^= (uint32_t)((cc & 7) << 4); \
        b[NS][j][kk] = *(const bf16x8*)(Bs + off); }

#define MM(MH, NS, AF) do { \
    __builtin_amdgcn_s_setprio(1); \
    _Pragma("unroll") for (int i = 0; i < 4; ++i) \
    _Pragma("unroll") for (int j = 0; j < 2; ++j) \
    _Pragma("unroll") for (int kk = 0; kk < 2; ++kk) \
        acc[MH][NS][i][j] = __builtin_amdgcn_mfma_f32_16x16x32_bf16(AF[i][kk], b[NS][j][kk], acc[MH][NS][i][j], 0, 0, 0); \
    __builtin_amdgcn_s_setprio(0); } while (0)

#define TILE(T, CUR, NB) do { \
    const int t1_ = (T) + 1; const bool st_ = (t1_ < 16); \
    bf16x8 a0[4][2], a1[4][2], b[2][2][2]; \
    /* P0 */ \
    RDA(a0, 0, CUR); RDB(0, CUR); \
    if (st_) { STA(t1_, NB, 0); STA(t1_, NB, 2); } \
    SBAR; MM(0, 0, a0); WVMC(4); SBAR; \
    /* P1 */ \
    RDB(1, CUR); \
    if (st_) { STB(t1_, NB, 0); STB(t1_, NB, 1); } \
    SBAR; MM(0, 1, a0); WVMC(4); SBAR; \
    /* P2 */ \
    RDA(a1, 1, CUR); \
    if (st_) { STB(t1_, NB, 2); STB(t1_, NB, 3); } \
    SBAR; MM(1, 0, a1); SBAR; \
    /* P3 */ \
    if (st_) { STA(t1_, NB, 1); STA(t1_, NB, 3); } \
    SBAR; MM(1, 1, a1); WVMC(4); SBAR; \
} while (0)

    f32x4 acc[2][2][4][2] = {};

    // prologue: stage tile 0 into buf 0, order A02, B01, B23, A13
    STA(0, 0, 0); STA(0, 0, 2);
    STB(0, 0, 0); STB(0, 0, 1);
    STB(0, 0, 2); STB(0, 0, 3);
    STA(0, 0, 1); STA(0, 0, 3);
    WVMC(0); SBAR;

    for (int t = 0; t < 16; t += 2) {
        TILE(t, 0, 1);
        TILE(t + 1, 1, 0);
    }
    WVMC(0);   // drain staging before smem reuse

    // ---- epilogue: own = sum_j w[row][2wn+j] * acc; tree-reduce over wn; store y
    float* P0 = (float*)smem;               // [2][256][17] f32
    float* P1 = (float*)(smem + 34816);
    const float* wrow = iw + (size_t)m0 * NIN;

    float own[2][2][4][4];
#pragma unroll
    for (int mh = 0; mh < 2; ++mh)
#pragma unroll
        for (int i = 0; i < 4; ++i)
#pragma unroll
            for (int e = 0; e < 4; ++e) {
                const int row = wm * 128 + mh * 64 + i * 16 + lq * 4 + e;
                const float w0 = wrow[row * NIN + wn * 2 + 0];
                const float w1 = wrow[row * NIN + wn * 2 + 1];
#pragma unroll
                for (int ns = 0; ns < 2; ++ns)
                    own[mh][ns][i][e] = w0 * acc[mh][ns][i][0][e] + w1 * acc[mh][ns][i][1][e];
            }

#define PIX(NS, ROW) ((NS) * (256 * 17) + (ROW) * 17 + l15)
    SBAR;   // all waves past K-loop before smem overwrite
    if (wn == 1 || wn == 3) {
        float* P = (wn == 1) ? P0 : P1;
#pragma unroll
        for (int mh = 0; mh < 2; ++mh)
#pragma unroll
            for (int ns = 0; ns < 2; ++ns)
#pragma unroll
                for (int i = 0; i < 4; ++i)
#pragma unroll
                    for (int e = 0; e < 4; ++e) {
                        const int row = wm * 128 + mh * 64 + i * 16 + lq * 4 + e;
                        P[PIX(ns, row)] = own[mh][ns][i][e];
                    }
    }
    SBARL;
    if (wn == 2) {
#pragma unroll
        for (int mh = 0; mh < 2; ++mh)
#pragma unroll
            for (int ns = 0; ns < 2; ++ns)
#pragma unroll
                for (int i = 0; i < 4; ++i)
#pragma unroll
                    for (int e = 0; e < 4; ++e) {
                        const int row = wm * 128 + mh * 64 + i * 16 + lq * 4 + e;
                        P1[PIX(ns, row)] += own[mh][ns][i][e];
                    }
    }
    SBARL;
    if (wn == 0) {
#pragma unroll
        for (int mh = 0; mh < 2; ++mh)
#pragma unroll
            for (int ns = 0; ns < 2; ++ns)
#pragma unroll
                for (int i = 0; i < 4; ++i)
#pragma unroll
                    for (int e = 0; e < 4; ++e) {
                        const int row = wm * 128 + mh * 64 + i * 16 + lq * 4 + e;
                        const float s = own[mh][ns][i][e] + P0[PIX(ns, row)] + P1[PIX(ns, row)];
                        y[(size_t)(m0 + row) * R_DIM + (2 * by + ns) * 16 + l15] = s;
                    }
    }
#undef PIX
#undef TILE
#undef MM
#undef RDB
#undef RDA
#undef STB
#undef STA
}

// ---------------- kernel 2: Householder chain, in-place on d_out
__global__ __launch_bounds__(512)
void house(float* __restrict__ y, const int* __restrict__ pidx,
           const float* __restrict__ pn) {
    const int tid = threadIdx.x;
    const int row = tid >> 3;
    const int cg  = tid & 7;
    const int c0  = cg * 16;
    const int tok = blockIdx.x * 64 + row;

    float yv[16];
#pragma unroll
    for (int q = 0; q < 4; ++q) {
        const f32x4 s = *(const f32x4*)&y[(size_t)tok * R_DIM + c0 + q * 4];
        yv[q * 4 + 0] = s[0]; yv[q * 4 + 1] = s[1]; yv[q * 4 + 2] = s[2]; yv[q * 4 + 3] = s[3];
    }

    const int4 idx4 = *(const int4*)&pidx[tok * 4];
    const int idxs[4] = { idx4.x, idx4.y, idx4.z, idx4.w };

#pragma unroll
    for (int k = 0; k < 4; ++k) {
        const float* vptr = &pn[(size_t)idxs[k] * R_DIM + c0];
        float v[16];
#pragma unroll
        for (int q = 0; q < 4; ++q) {
            const f32x4 vv4 = *(const f32x4*)&vptr[q * 4];
            v[q * 4 + 0] = vv4[0]; v[q * 4 + 1] = vv4[1];
            v[q * 4 + 2] = vv4[2]; v[q * 4 + 3] = vv4[3];
        }
        float vy = 0.f, vv = 0.f;
#pragma unroll
        for (int j = 0; j < 16; ++j) { vy += v[j] * yv[j]; vv += v[j] * v[j]; }
#pragma unroll
        for (int o = 1; o < 8; o <<= 1) {
            vy += __shfl_xor(vy, o);
            vv += __shfl_xor(vv, o);
        }
        const float s = 2.0f * vy / (vv + 1e-8f);
#pragma unroll
        for (int j = 0; j < 16; ++j) yv[j] -= s * v[j];
    }

#pragma unroll
    for (int q = 0; q < 4; ++q) {
        f32x4 o; o[0] = yv[q*4+0]; o[1] = yv[q*4+1]; o[2] = yv[q*4+2]; o[3] = yv[q*4+3];
        *(f32x4*)&y[(size_t)tok * R_DIM + c0 + q * 4] = o;
    }
}

extern "C" void kernel_launch(void* const* d_in, const int* in_sizes, int n_in,
                              void* d_out, int out_size, void* d_ws, size_t ws_size,
                              hipStream_t stream) {
    const float* x   = (const float*)d_in[0];   // [4,4096,1024]
    const float* iw  = (const float*)d_in[1];   // [4,4096,8]
    const int*   pix = (const int*)d_in[2];     // [4,4096,4]
    const float* inn = (const float*)d_in[3];   // [8,1024,128]
    const float* pn  = (const float*)d_in[4];   // [32,128]
    float* out = (float*)d_out;                 // [4,4096,128] f32

    u16* xb  = (u16*)d_ws;                                  // 32 MB
    u16* Bt2 = (u16*)((char*)d_ws + (size_t)(32 << 20));    // 2 MB

    prep<<<8320, 256, 0, stream>>>(x, xb, inn, Bt2);
    gemm8<<<256, 512, 0, stream>>>(xb, Bt2, iw, out);
    house<<<256, 512, 0, stream>>>(out, pix, pn);
}